// Round 4
// baseline (142.980 us; speedup 1.0000x reference)
//
#include <hip/hip_runtime.h>
#include <hip/hip_bf16.h>

#define NUM_CLASSES 64
#define BATCH 16
#define CHAN 3
#define HW (512 * 512)
#define BPB 64          // blocks per batch image -> 1024 blocks total
#define THREADS 256
#define NITER 4         // pipelined iterations per thread (GPB/THREADS)
#define NREP 4          // histogram replicas to cut LDS-atomic contention
#define CPAD 8          // pad per replica row: stagger replica banks

// ---------------------------------------------------------------------------
// Kernel 1: per-(batch,class) sums/counts of per-pixel channel-summed
// |in - tgt|.  Software-pipelined: stage s loads iteration i+1 while
// iteration i computes -> each wave keeps ~7KB of loads in flight
// continuously (MLP), instead of the compiler's 2-loads-per-waitcnt batches.
// __launch_bounds__(256,2) gives the allocator room (<=256 VGPR) so the
// prefetch stage is NOT sunk back to its uses.
// ---------------------------------------------------------------------------
__global__ __launch_bounds__(THREADS, 2) void frl_accum(
    const float4* __restrict__ inp,   // [B,C,H,W] as float4
    const float4* __restrict__ tgt,
    const int4* __restrict__ mask,    // [B,H,W] as int4
    float* __restrict__ g_sum,        // [B*64]
    unsigned int* __restrict__ g_cnt) // [B*64]
{
    __shared__ float s_sum[NREP][NUM_CLASSES + CPAD];
    __shared__ unsigned int s_cnt[NREP][NUM_CLASSES + CPAD];
    const int t = threadIdx.x;

    const int b   = blockIdx.x / BPB;
    const int blk = blockIdx.x % BPB;
    const int GPB = HW / 4 / BPB;             // 1024 float4-groups per block
    const int rep = t & (NREP - 1);

    const int g0    = blk * GPB;
    const int CS    = HW / 4;                 // channel stride in float4
    const int cbase = b * (CHAN * CS) + g0 + t;
    const int mbase = b * CS + g0 + t;        // mask stride HW/4 int4 = CS

    int4   ms[2];
    float4 ai[2][CHAN];
    float4 at[2][CHAN];

    // ---- prologue: issue stage-0 loads BEFORE LDS init so init+barrier
    //      overlap the load latency ----
    ms[0]    = mask[mbase];
    ai[0][0] = inp[cbase + 0 * CS];
    ai[0][1] = inp[cbase + 1 * CS];
    ai[0][2] = inp[cbase + 2 * CS];
    at[0][0] = tgt[cbase + 0 * CS];
    at[0][1] = tgt[cbase + 1 * CS];
    at[0][2] = tgt[cbase + 2 * CS];

    for (int i = t; i < NREP * (NUM_CLASSES + CPAD); i += THREADS) {
        ((float*)s_sum)[i] = 0.0f;
        ((unsigned int*)s_cnt)[i] = 0u;
    }
    __syncthreads();

    #pragma unroll
    for (int it = 0; it < NITER; ++it) {
        const int cur = it & 1;
        const int nxt = cur ^ 1;
        if (it < NITER - 1) {
            const int off = (it + 1) * THREADS;
            ms[nxt]    = mask[mbase + off];
            ai[nxt][0] = inp[cbase + 0 * CS + off];
            ai[nxt][1] = inp[cbase + 1 * CS + off];
            ai[nxt][2] = inp[cbase + 2 * CS + off];
            at[nxt][0] = tgt[cbase + 0 * CS + off];
            at[nxt][1] = tgt[cbase + 1 * CS + off];
            at[nxt][2] = tgt[cbase + 2 * CS + off];
        }
        const float l0 = fabsf(ai[cur][0].x - at[cur][0].x)
                       + fabsf(ai[cur][1].x - at[cur][1].x)
                       + fabsf(ai[cur][2].x - at[cur][2].x);
        const float l1 = fabsf(ai[cur][0].y - at[cur][0].y)
                       + fabsf(ai[cur][1].y - at[cur][1].y)
                       + fabsf(ai[cur][2].y - at[cur][2].y);
        const float l2 = fabsf(ai[cur][0].z - at[cur][0].z)
                       + fabsf(ai[cur][1].z - at[cur][1].z)
                       + fabsf(ai[cur][2].z - at[cur][2].z);
        const float l3 = fabsf(ai[cur][0].w - at[cur][0].w)
                       + fabsf(ai[cur][1].w - at[cur][1].w)
                       + fabsf(ai[cur][2].w - at[cur][2].w);
        const int4 m = ms[cur];
        atomicAdd(&s_sum[rep][m.x], l0);
        atomicAdd(&s_sum[rep][m.y], l1);
        atomicAdd(&s_sum[rep][m.z], l2);
        atomicAdd(&s_sum[rep][m.w], l3);
        atomicAdd(&s_cnt[rep][m.x], 1u);
        atomicAdd(&s_cnt[rep][m.y], 1u);
        atomicAdd(&s_cnt[rep][m.z], 1u);
        atomicAdd(&s_cnt[rep][m.w], 1u);
    }

    __syncthreads();
    if (t < NUM_CLASSES) {
        float fs = 0.0f;
        unsigned int cs = 0u;
        #pragma unroll
        for (int r = 0; r < NREP; ++r) { fs += s_sum[r][t]; cs += s_cnt[r][t]; }
        atomicAdd(&g_sum[b * NUM_CLASSES + t], fs);
        atomicAdd(&g_cnt[b * NUM_CLASSES + t], cs);
    }
}

// ---------------------------------------------------------------------------
// Kernel 2: avg = sum / max(3*cnt,1); max over avg; result =
//   ( Σ sums + Σ sums * clip(avg/max,0,1) ) / (B*C*H*W)     (BETA = 1)
// ---------------------------------------------------------------------------
__global__ __launch_bounds__(256) void frl_finalize(
    const float* __restrict__ g_sum,
    const unsigned int* __restrict__ g_cnt,
    float* __restrict__ out)
{
    const int NSEG = BATCH * NUM_CLASSES;     // 1024
    __shared__ float s_avg[BATCH * NUM_CLASSES];
    __shared__ float red[256];
    const int t = threadIdx.x;

    float lmax = 0.0f;
    for (int s = t; s < NSEG; s += 256) {
        const float sum = g_sum[s];
        const float cnt = (float)g_cnt[s];
        const float avg = sum / fmaxf(cnt * (float)CHAN, 1.0f);
        s_avg[s] = avg;
        lmax = fmaxf(lmax, avg);
    }
    red[t] = lmax;
    __syncthreads();
    for (int off = 128; off > 0; off >>= 1) {
        if (t < off) red[t] = fmaxf(red[t], red[t + off]);
        __syncthreads();
    }
    const float maxavg = fmaxf(red[0], 1e-30f);
    __syncthreads();

    float part = 0.0f;
    for (int s = t; s < NSEG; s += 256) {
        const float w = fminf(fmaxf(s_avg[s] / maxavg, 0.0f), 1.0f);
        part += g_sum[s] * (1.0f + w);
    }
    red[t] = part;
    __syncthreads();
    for (int off = 128; off > 0; off >>= 1) {
        if (t < off) red[t] += red[t + off];
        __syncthreads();
    }
    if (t == 0) {
        out[0] = red[0] / (float)((size_t)BATCH * CHAN * HW);
    }
}

extern "C" void kernel_launch(void* const* d_in, const int* in_sizes, int n_in,
                              void* d_out, int out_size, void* d_ws, size_t ws_size,
                              hipStream_t stream) {
    const float4* inp = (const float4*)d_in[0];
    const float4* tgt = (const float4*)d_in[1];
    const int4* mask  = (const int4*)d_in[2];

    float* g_sum        = (float*)d_ws;
    unsigned int* g_cnt = (unsigned int*)((char*)d_ws + BATCH * NUM_CLASSES * sizeof(float));

    hipMemsetAsync(d_ws, 0, 2 * BATCH * NUM_CLASSES * sizeof(float), stream);
    frl_accum<<<BATCH * BPB, THREADS, 0, stream>>>(inp, tgt, mask, g_sum, g_cnt);
    frl_finalize<<<1, 256, 0, stream>>>(g_sum, g_cnt, (float*)d_out);
}